// Round 3
// baseline (1778.437 us; speedup 1.0000x reference)
//
#include <hip/hip_runtime.h>

#define NU 100000
#define NI 100000
#define NE 500000
#define HD 128

// ---------------- src-degree histograms (3 int arrays of 100000) ----------------
__global__ __launch_bounds__(256) void count_src3(
    const int* __restrict__ s0, const int* __restrict__ s1,
    const int* __restrict__ s2, int* __restrict__ cnt)
{
    long long t = (long long)blockIdx.x * 256 + threadIdx.x;
    if (t >= 3LL * NE) return;
    int a = (int)(t / NE);
    int e = (int)(t - (long long)a * NE);
    const int* p = (a == 0) ? s0 : (a == 1) ? s1 : s2;
    atomicAdd(&cnt[a * 100000 + p[e]], 1);
}

// cdeg (6 x 100000 ints) -> rs (6 x 100000 floats) = rsqrt(max(deg,1))
__global__ __launch_bounds__(256) void rs_finalize(const int* __restrict__ cdeg,
                                                   float* __restrict__ rs)
{
    int t = blockIdx.x * 256 + threadIdx.x;
    if (t < 600000) rs[t] = rsqrtf(fmaxf((float)cdeg[t], 1.0f));
}

// ---------------- CSR build ----------------
__global__ __launch_bounds__(256) void count_dst(const int* __restrict__ dst,
                                                 int* __restrict__ cnt)
{
    int e = blockIdx.x * 256 + threadIdx.x;
    if (e < NE) atomicAdd(&cnt[dst[e]], 1);
}

__global__ __launch_bounds__(256) void scan_block(const int* __restrict__ cnt, int n,
                                                  int* __restrict__ rp,
                                                  int* __restrict__ bsum)
{
    __shared__ int s[256];
    int gid = blockIdx.x * 256 + threadIdx.x;
    int v = (gid < n) ? cnt[gid] : 0;
    s[threadIdx.x] = v;
    __syncthreads();
#pragma unroll
    for (int off = 1; off < 256; off <<= 1) {
        int t = (threadIdx.x >= off) ? s[threadIdx.x - off] : 0;
        __syncthreads();
        s[threadIdx.x] += t;
        __syncthreads();
    }
    if (gid < n) rp[gid] = s[threadIdx.x] - v;   // exclusive
    if (threadIdx.x == 255) bsum[blockIdx.x] = s[255];
}

__global__ __launch_bounds__(512) void scan_bsums(int* __restrict__ bsum, int nb)
{
    __shared__ int s[512];
    int v = (threadIdx.x < nb) ? bsum[threadIdx.x] : 0;
    s[threadIdx.x] = v;
    __syncthreads();
#pragma unroll
    for (int off = 1; off < 512; off <<= 1) {
        int t = (threadIdx.x >= off) ? s[threadIdx.x - off] : 0;
        __syncthreads();
        s[threadIdx.x] += t;
        __syncthreads();
    }
    if (threadIdx.x < nb) bsum[threadIdx.x] = s[threadIdx.x] - v;
    if (threadIdx.x == 0) bsum[nb] = s[nb - 1];  // total
}

__global__ __launch_bounds__(256) void scan_add(int* __restrict__ rp,
                                                const int* __restrict__ bsum,
                                                int n, int nb)
{
    int gid = blockIdx.x * 256 + threadIdx.x;
    if (gid < n) rp[gid] += bsum[blockIdx.x];
    if (gid == 0) rp[n] = bsum[nb];
}

__global__ __launch_bounds__(256) void csr_fill(const int* __restrict__ src,
                                                const int* __restrict__ dst,
                                                const int* __restrict__ rp,
                                                int* __restrict__ cursor,
                                                int* __restrict__ eidx)
{
    int e = blockIdx.x * 256 + threadIdx.x;
    if (e >= NE) return;
    int d = dst[e];
    int pos = rp[d] + atomicAdd(&cursor[d], 1);
    eidx[pos] = src[e];
}

// ---- CSR gather: m[d] = rs_in[d] * sum_{e in csr[d]} x[src_e] * rs_out[src_e] ----
__global__ __launch_bounds__(256) void gather_scaled(
    const float* __restrict__ x, const float* __restrict__ rs_out,
    const float* __restrict__ rs_in,
    const int* __restrict__ rp, const int* __restrict__ eidx,
    float* __restrict__ m, int n)
{
    int row = blockIdx.x * 8 + (threadIdx.x >> 5);
    int c = (threadIdx.x & 31) * 4;
    if (row >= n) return;
    int beg = rp[row], end = rp[row + 1];
    float ax = 0.f, ay = 0.f, az = 0.f, aw = 0.f;
    int p = beg;
    for (; p + 2 <= end; p += 2) {
        int s0 = eidx[p], s1 = eidx[p + 1];
        float r0 = rs_out[s0], r1 = rs_out[s1];
        float4 v0 = *(const float4*)(x + (long long)s0 * HD + c);
        float4 v1 = *(const float4*)(x + (long long)s1 * HD + c);
        ax = fmaf(v0.x, r0, ax); ay = fmaf(v0.y, r0, ay);
        az = fmaf(v0.z, r0, az); aw = fmaf(v0.w, r0, aw);
        ax = fmaf(v1.x, r1, ax); ay = fmaf(v1.y, r1, ay);
        az = fmaf(v1.z, r1, az); aw = fmaf(v1.w, r1, aw);
    }
    if (p < end) {
        int s0 = eidx[p];
        float r0 = rs_out[s0];
        float4 v0 = *(const float4*)(x + (long long)s0 * HD + c);
        ax = fmaf(v0.x, r0, ax); ay = fmaf(v0.y, r0, ay);
        az = fmaf(v0.z, r0, az); aw = fmaf(v0.w, r0, aw);
    }
    float ri = rs_in[row];
    *(float4*)(m + (long long)row * HD + c) =
        make_float4(ax * ri, ay * ri, az * ri, aw * ri);
}

// ---------------- C[M x 128] = A[M x K] @ W[K x 128], fused epilogue ----------------
// 128x128 tile, 256 threads, 8x8 per-thread register tile (cols c0..c0+3, c0+64..c0+67)
__global__ __launch_bounds__(256) void gemm128(
    const float* __restrict__ A, int K, int M,
    const float* __restrict__ W,
    const float* __restrict__ bias,
    int do_relu, int do_accum,
    float* __restrict__ C)
{
    __shared__ float sA[128 * 32];
    __shared__ float sW[32 * 128];
    const int tid = threadIdx.x;
    const int row0 = blockIdx.x * 128;
    const int tx = tid & 15;
    const int ty = tid >> 4;
    const int c0 = tx * 4;

    float acc[8][8];
#pragma unroll
    for (int r = 0; r < 8; ++r)
#pragma unroll
        for (int j = 0; j < 8; ++j) acc[r][j] = 0.f;

    const int nk = (K + 31) >> 5;
    for (int kc = 0; kc < nk; ++kc) {
        const int k0 = kc << 5;
        // stage A tile: 128 rows x 32 k (4 float4 per thread)
#pragma unroll
        for (int i = 0; i < 4; ++i) {
            int id = tid + i * 256;       // 0..1023
            int r = id >> 3;              // row 0..127
            int kq = (id & 7) << 2;       // k-offset 0..28
            int row = row0 + r;
            int k = k0 + kq;
            float4 v = make_float4(0.f, 0.f, 0.f, 0.f);
            if (row < M) {
                if (k + 3 < K) {
                    v = *(const float4*)(A + (long long)row * K + k);
                } else {
                    float q0 = (k + 0 < K) ? A[(long long)row * K + k + 0] : 0.f;
                    float q1 = (k + 1 < K) ? A[(long long)row * K + k + 1] : 0.f;
                    float q2 = (k + 2 < K) ? A[(long long)row * K + k + 2] : 0.f;
                    float q3 = (k + 3 < K) ? A[(long long)row * K + k + 3] : 0.f;
                    v = make_float4(q0, q1, q2, q3);
                }
            }
            *(float4*)(sA + r * 32 + kq) = v;
        }
        // stage W tile: 32 k x 128 cols (4 float4 per thread)
#pragma unroll
        for (int i = 0; i < 4; ++i) {
            int id = tid + i * 256;
            int kr = id >> 5;             // k row 0..31
            int cq = (id & 31) << 2;      // col 0..124
            int k = k0 + kr;
            float4 v = make_float4(0.f, 0.f, 0.f, 0.f);
            if (k < K) v = *(const float4*)(W + (long long)k * 128 + cq);
            *(float4*)(sW + kr * 128 + cq) = v;
        }
        __syncthreads();
#pragma unroll
        for (int kq = 0; kq < 8; ++kq) {
            float wf[4][8];
#pragma unroll
            for (int kk = 0; kk < 4; ++kk) {
                float4 w0 = *(const float4*)(sW + (kq * 4 + kk) * 128 + c0);
                float4 w1 = *(const float4*)(sW + (kq * 4 + kk) * 128 + c0 + 64);
                wf[kk][0] = w0.x; wf[kk][1] = w0.y; wf[kk][2] = w0.z; wf[kk][3] = w0.w;
                wf[kk][4] = w1.x; wf[kk][5] = w1.y; wf[kk][6] = w1.z; wf[kk][7] = w1.w;
            }
#pragma unroll
            for (int r = 0; r < 8; ++r) {
                float4 av = *(const float4*)(sA + (ty * 8 + r) * 32 + kq * 4);
                float af[4] = {av.x, av.y, av.z, av.w};
#pragma unroll
                for (int kk = 0; kk < 4; ++kk)
#pragma unroll
                    for (int j = 0; j < 8; ++j)
                        acc[r][j] = fmaf(af[kk], wf[kk][j], acc[r][j]);
            }
        }
        __syncthreads();
    }

    float bv[8] = {0.f, 0.f, 0.f, 0.f, 0.f, 0.f, 0.f, 0.f};
    if (bias) {
        float4 b0 = *(const float4*)(bias + c0);
        float4 b1 = *(const float4*)(bias + c0 + 64);
        bv[0] = b0.x; bv[1] = b0.y; bv[2] = b0.z; bv[3] = b0.w;
        bv[4] = b1.x; bv[5] = b1.y; bv[6] = b1.z; bv[7] = b1.w;
    }
#pragma unroll
    for (int r = 0; r < 8; ++r) {
        int row = row0 + ty * 8 + r;
        if (row < M) {
            float o[8];
#pragma unroll
            for (int j = 0; j < 8; ++j) {
                float v = acc[r][j] + bv[j];
                if (do_relu) v = fmaxf(v, 0.f);
                o[j] = v;
            }
            float* cp = C + (long long)row * 128;
            if (do_accum) {
                float4 p0 = *(const float4*)(cp + c0);
                float4 p1 = *(const float4*)(cp + c0 + 64);
                o[0] += p0.x; o[1] += p0.y; o[2] += p0.z; o[3] += p0.w;
                o[4] += p1.x; o[5] += p1.y; o[6] += p1.z; o[7] += p1.w;
            }
            *(float4*)(cp + c0)      = make_float4(o[0], o[1], o[2], o[3]);
            *(float4*)(cp + c0 + 64) = make_float4(o[4], o[5], o[6], o[7]);
        }
    }
}

static inline void build_csr(const int* src, const int* dst, int n_dst,
                             int* cnt, int* rp, int* cursor, int* eidx,
                             int* bsum, hipStream_t stream)
{
    const int nb = (n_dst + 255) / 256;
    count_dst<<<(NE + 255) / 256, 256, 0, stream>>>(dst, cnt);
    scan_block<<<nb, 256, 0, stream>>>(cnt, n_dst, rp, bsum);
    scan_bsums<<<1, 512, 0, stream>>>(bsum, nb);
    scan_add<<<nb, 256, 0, stream>>>(rp, bsum, n_dst, nb);
    csr_fill<<<(NE + 255) / 256, 256, 0, stream>>>(src, dst, rp, cursor, eidx);
}

extern "C" void kernel_launch(void* const* d_in, const int* in_sizes, int n_in,
                              void* d_out, int out_size, void* d_ws, size_t ws_size,
                              hipStream_t stream)
{
    const float* feat_user = (const float*)d_in[0];
    const float* feat_item = (const float*)d_in[1];
    const int* src_uu = (const int*)d_in[2];
    const int* dst_uu = (const int*)d_in[3];
    const int* src_ui = (const int*)d_in[4];
    const int* dst_ui = (const int*)d_in[5];
    const int* src_iu = (const int*)d_in[6];
    const int* dst_iu = (const int*)d_in[7];
    const float* We_u = (const float*)d_in[8];
    const float* be_u = (const float*)d_in[9];
    const float* We_i = (const float*)d_in[10];
    const float* be_i = (const float*)d_in[11];

    float* hu = (float*)d_out;                 // [NU x 128]
    float* hi = hu + (size_t)NU * HD;          // [NI x 128]

    float* ws   = (float*)d_ws;
    float* m_uu = ws;                          // [NU x 128] dst=user
    float* m_ui = m_uu + (size_t)NU * HD;      // [NI x 128] dst=item
    float* m_iu = m_ui + (size_t)NI * HD;      // [NU x 128] dst=user
    float* rs   = m_iu + (size_t)NU * HD;      // 6 x 100000 floats
    float* rs_out_uu = rs + 0;
    float* rs_out_ui = rs + 100000;
    float* rs_out_iu = rs + 200000;
    float* rs_in_uu  = rs + 300000;
    float* rs_in_ui  = rs + 400000;
    float* rs_in_iu  = rs + 500000;

    int* ib = (int*)(rs + 600000);
    int* cdeg    = ib;                 ib += 600000;   // 3 src-counts, 3 dst-counts
    int* cursor  = ib;                 ib += 300000;   // per-etype fill cursors
    int* rp_uu   = ib;                 ib += 100001;
    int* rp_ui   = ib;                 ib += 100001;
    int* rp_iu   = ib;                 ib += 100001;
    int* ei_uu   = ib;                 ib += NE;
    int* ei_ui   = ib;                 ib += NE;
    int* ei_iu   = ib;                 ib += NE;
    int* bsum    = ib;                 ib += 1024;

    // zero count + cursor regions (3.6 MB), then histogram src degrees
    hipMemsetAsync(cdeg, 0, 900000 * sizeof(int), stream);
    count_src3<<<(3 * NE + 255) / 256, 256, 0, stream>>>(src_uu, src_ui, src_iu, cdeg);

    // CSR (dst-major) per etype; count_dst doubles as in-degree histogram
    build_csr(src_uu, dst_uu, NU, cdeg + 300000, rp_uu, cursor,          ei_uu, bsum, stream);
    build_csr(src_ui, dst_ui, NI, cdeg + 400000, rp_ui, cursor + 100000, ei_ui, bsum, stream);
    build_csr(src_iu, dst_iu, NU, cdeg + 500000, rp_iu, cursor + 200000, ei_iu, bsum, stream);

    rs_finalize<<<(600000 + 255) / 256, 256, 0, stream>>>(cdeg, rs);

    // HeteroLinear embed
    gemm128<<<(NU + 127) / 128, 256, 0, stream>>>(feat_user, 256, NU, We_u, be_u, 0, 0, hu);
    gemm128<<<(NI + 127) / 128, 256, 0, stream>>>(feat_item, 300, NI, We_i, be_i, 0, 0, hi);

    const int gat_blocks = (NU + 7) / 8;   // NU == NI
    for (int l = 0; l < 3; ++l) {
        const float* W_uu = (const float*)d_in[12 + 6 * l + 0];
        const float* b_uu = (const float*)d_in[12 + 6 * l + 1];
        const float* W_ui = (const float*)d_in[12 + 6 * l + 2];
        const float* b_ui = (const float*)d_in[12 + 6 * l + 3];
        const float* W_iu = (const float*)d_in[12 + 6 * l + 4];
        const float* b_iu = (const float*)d_in[12 + 6 * l + 5];
        const int relu = (l < 2) ? 1 : 0;

        // m[d] = rs_in[d] * sum over in-edges of x[src]*rs_out[src]
        gather_scaled<<<gat_blocks, 256, 0, stream>>>(hu, rs_out_uu, rs_in_uu, rp_uu, ei_uu, m_uu, NU);
        gather_scaled<<<gat_blocks, 256, 0, stream>>>(hu, rs_out_ui, rs_in_ui, rp_ui, ei_ui, m_ui, NI);
        gather_scaled<<<gat_blocks, 256, 0, stream>>>(hi, rs_out_iu, rs_in_iu, rp_iu, ei_iu, m_iu, NU);
        // out = relu(m @ W + b), summed per dst ntype
        gemm128<<<(NU + 127) / 128, 256, 0, stream>>>(m_uu, HD, NU, W_uu, b_uu, relu, 0, hu);
        gemm128<<<(NU + 127) / 128, 256, 0, stream>>>(m_iu, HD, NU, W_iu, b_iu, relu, 1, hu);
        gemm128<<<(NI + 127) / 128, 256, 0, stream>>>(m_ui, HD, NI, W_ui, b_ui, relu, 0, hi);
    }
}